// Round 2
// baseline (289.921 us; speedup 1.0000x reference)
//
#include <hip/hip_runtime.h>
#include <cstdint>

#define B_ROWS 32768
#define DIM    256
#define KCODES 1024
#define NSPLIT 4

typedef _Float16 f16x8 __attribute__((ext_vector_type(8)));
typedef float    f32x4 __attribute__((ext_vector_type(4)));

// ws layout:
//   [0, 512K)        cb_hi  (fp16, per-code 512B rows, 16B-granule XOR-swizzled)
//   [512K, 1M)       cb_lo  (fp16, scaled x2048, same swizzle)
//   [1M, 1M+4K)      inv_norm (float[1024])
//   [1M+4K, ...)     cand   (float2[NSPLIT][B_ROWS] = {dot, bitcast(k)})

// ---------------- prep: codebook -> fp16 hi/lo (swizzled) + 1/norm ----------------
__global__ __launch_bounds__(64) void vq_prep(const float* __restrict__ cb,
                                              _Float16* __restrict__ hi,
                                              _Float16* __restrict__ lo,
                                              float* __restrict__ inv_norm) {
  const int k = blockIdx.x;
  const int lane = threadIdx.x;
  float4 c = reinterpret_cast<const float4*>(cb)[k * 64 + lane];
  float nrm = c.x * c.x + c.y * c.y + c.z * c.z + c.w * c.w;
#pragma unroll
  for (int off = 32; off; off >>= 1) nrm += __shfl_xor(nrm, off);
  if (lane == 0) inv_norm[k] = 1.0f / nrm;

  float f[4] = {c.x, c.y, c.z, c.w};
  _Float16 h[4], l[4];
#pragma unroll
  for (int i = 0; i < 4; ++i) {
    h[i] = (_Float16)f[i];
    l[i] = (_Float16)((f[i] - (float)h[i]) * 2048.0f);
  }
  // granule swizzle: phys = g ^ (code & 15) within the code's 512B row
  const int phys = (lane >> 1) ^ (k & 15);
  const int byteoff = k * 512 + phys * 16 + (lane & 1) * 8;
  *reinterpret_cast<uint2*>((char*)hi + byteoff) = *reinterpret_cast<uint2*>(h);
  *reinterpret_cast<uint2*>((char*)lo + byteoff) = *reinterpret_cast<uint2*>(l);
}

__device__ __forceinline__ void gld16(const void* g, void* l) {
  __builtin_amdgcn_global_load_lds(
      (const __attribute__((address_space(1))) uint32_t*)g,
      (__attribute__((address_space(3))) uint32_t*)l, 16, 0, 0);
}

// ---------------- main: split-fp16 MFMA GEMM + per-split argmax candidates ----------------
// K-split x4: block (rowblk, split) covers rows [rowblk*128, +128) x codes [split*256, +256).
__global__ __launch_bounds__(256, 4) void vq_main(const float* __restrict__ emb,
                                                  const _Float16* __restrict__ cbh,
                                                  const _Float16* __restrict__ cbl,
                                                  const float* __restrict__ inv_g,
                                                  float2* __restrict__ cand) {
  __shared__ uint4 Btile[2][1024];   // 2 x 16KB: [0,8K) hi, [8K,16K) lo
  __shared__ float inv_s[KCODES];

  const int flat = threadIdx.x;
  const int wave = flat >> 6;
  const int lane = flat & 63;
  const int quad = lane >> 4;
  const int lr   = lane & 15;

  const int split  = blockIdx.x & (NSPLIT - 1);
  const int rowblk = blockIdx.x >> 2;
  const int t0 = split * 16;         // 16 t-iters of 16 codes each = 256 codes

  reinterpret_cast<float4*>(inv_s)[flat] = reinterpret_cast<const float4*>(inv_g)[flat];

  // A fragments: 32 rows/wave (2 subtiles of 16), whole K-depth, hi+lo, in registers.
  f16x8 Ah[2][8], Al[2][8];
  const int row0 = rowblk * 128 + wave * 32;
#pragma unroll
  for (int s = 0; s < 2; ++s) {
    const float* rp = emb + (size_t)(row0 + s * 16 + lr) * DIM;
#pragma unroll
    for (int c = 0; c < 8; ++c) {
      const float* p = rp + c * 32 + quad * 8;
      float4 f0 = *reinterpret_cast<const float4*>(p);
      float4 f1 = *reinterpret_cast<const float4*>(p + 4);
      float f[8] = {f0.x, f0.y, f0.z, f0.w, f1.x, f1.y, f1.z, f1.w};
      f16x8 h, l;
#pragma unroll
      for (int j = 0; j < 8; ++j) {
        _Float16 hv = (_Float16)f[j];
        h[j] = hv;
        l[j] = (_Float16)((f[j] - (float)hv) * 2048.0f);
      }
      Ah[s][c] = h;
      Al[s][c] = l;
    }
  }

  auto stage = [&](int buf, int t) {
    const char* srcH = (const char*)cbh + t * 8192;
    const char* srcL = (const char*)cbl + t * 8192;
    char* dst = (char*)&Btile[buf][0];
    const int off = flat * 16;
    gld16(srcH + off,        dst + off);
    gld16(srcH + 4096 + off, dst + 4096 + off);
    gld16(srcL + off,        dst + 8192 + off);
    gld16(srcL + 4096 + off, dst + 12288 + off);
  };
  stage(0, t0);

  float bg[2][4], bd[2][4];
  int   bk[2][4];
#pragma unroll
  for (int s = 0; s < 2; ++s)
#pragma unroll
    for (int r = 0; r < 4; ++r) { bg[s][r] = -1.0f; bd[s][r] = 0.0f; bk[s][r] = t0 * 16; }

  for (int t = t0; t < t0 + 16; ++t) {
    __syncthreads();
    if (t + 1 < t0 + 16) stage((t + 1) & 1, t + 1);
    const char* buf = (const char*)&Btile[t & 1][0];

    f32x4 accA0 = {0, 0, 0, 0}, accB0 = {0, 0, 0, 0};
    f32x4 accA1 = {0, 0, 0, 0}, accB1 = {0, 0, 0, 0};
#pragma unroll
    for (int c = 0; c < 8; ++c) {
      const int g = (((c * 4 + quad) ^ lr) * 16) + lr * 512;  // de-swizzled granule
      f16x8 bh = *reinterpret_cast<const f16x8*>(buf + g);
      f16x8 bl = *reinterpret_cast<const f16x8*>(buf + 8192 + g);
      accA0 = __builtin_amdgcn_mfma_f32_16x16x32_f16(Ah[0][c], bh, accA0, 0, 0, 0);
      accA1 = __builtin_amdgcn_mfma_f32_16x16x32_f16(Ah[1][c], bh, accA1, 0, 0, 0);
      accB0 = __builtin_amdgcn_mfma_f32_16x16x32_f16(Al[0][c], bh, accB0, 0, 0, 0);
      accB1 = __builtin_amdgcn_mfma_f32_16x16x32_f16(Al[1][c], bh, accB1, 0, 0, 0);
      accB0 = __builtin_amdgcn_mfma_f32_16x16x32_f16(Ah[0][c], bl, accB0, 0, 0, 0);
      accB1 = __builtin_amdgcn_mfma_f32_16x16x32_f16(Ah[1][c], bl, accB1, 0, 0, 0);
    }

    const int n = t * 16 + lr;             // C/D layout: col = lane&15
    const float inl = inv_s[n];
#pragma unroll
    for (int r = 0; r < 4; ++r) {
      float d0 = accA0[r] + accB0[r] * 4.8828125e-4f;   // 1/2048
      float g0 = d0 * d0 * inl;
      if (g0 > bg[0][r]) { bg[0][r] = g0; bd[0][r] = d0; bk[0][r] = n; }
      float d1 = accA1[r] + accB1[r] * 4.8828125e-4f;
      float g1 = d1 * d1 * inl;
      if (g1 > bg[1][r]) { bg[1][r] = g1; bd[1][r] = d1; bk[1][r] = n; }
    }
  }

  // cross-lane argmax over the 16 cols of each quad (rows = quad*4+reg per C layout)
#pragma unroll
  for (int s = 0; s < 2; ++s) {
#pragma unroll
    for (int r = 0; r < 4; ++r) {
      float g = bg[s][r]; int k = bk[s][r]; float d = bd[s][r];
#pragma unroll
      for (int m = 1; m < 16; m <<= 1) {
        float g2 = __shfl_xor(g, m);
        int   k2 = __shfl_xor(k, m);
        float d2 = __shfl_xor(d, m);
        if (g2 > g || (g2 == g && k2 < k)) { g = g2; k = k2; d = d2; }
      }
      if (lr == 0) {
        const int row = row0 + s * 16 + quad * 4 + r;
        cand[(size_t)split * B_ROWS + row] = make_float2(d, __int_as_float(k));
      }
    }
  }
}

// ---------------- reduce: pick best split candidate, write z + index ----------------
__global__ __launch_bounds__(256) void vq_reduce(const float2* __restrict__ cand,
                                                 const float* __restrict__ inv_g,
                                                 const float* __restrict__ cb,
                                                 float* __restrict__ out) {
  const int wave = threadIdx.x >> 6;
  const int lane = threadIdx.x & 63;
  const int row = blockIdx.x * 4 + wave;

  float best_g = -1.0f, best_d = 0.0f;
  int best_k = 0;
#pragma unroll
  for (int s = 0; s < NSPLIT; ++s) {
    float2 c = cand[(size_t)s * B_ROWS + row];
    int k = __float_as_int(c.y);
    float g = c.x * c.x * inv_g[k];
    if (g > best_g || (g == best_g && k < best_k)) {
      best_g = g; best_d = c.x; best_k = k;
    }
  }
  const float alpha = best_d * inv_g[best_k];
  float4 c4 = reinterpret_cast<const float4*>(cb)[best_k * 64 + lane];
  float4 z = {alpha * c4.x, alpha * c4.y, alpha * c4.z, alpha * c4.w};
  reinterpret_cast<float4*>(out)[(size_t)row * 64 + lane] = z;
  if (lane == 0) out[(size_t)B_ROWS * DIM + row] = (float)best_k;
}

extern "C" void kernel_launch(void* const* d_in, const int* in_sizes, int n_in,
                              void* d_out, int out_size, void* d_ws, size_t ws_size,
                              hipStream_t stream) {
  const float* emb = (const float*)d_in[0];
  const float* cb  = (const float*)d_in[1];
  _Float16* cbh = (_Float16*)d_ws;
  _Float16* cbl = (_Float16*)((char*)d_ws + (512 << 10));
  float*    inv = (float*)((char*)d_ws + (1 << 20));
  float2*   cand = (float2*)((char*)d_ws + (1 << 20) + 4096);

  vq_prep<<<KCODES, 64, 0, stream>>>(cb, cbh, cbl, inv);
  vq_main<<<(B_ROWS / 128) * NSPLIT, 256, 0, stream>>>(emb, cbh, cbl, inv, cand);
  vq_reduce<<<B_ROWS / 4, 256, 0, stream>>>(cand, inv, cb, (float*)d_out);
}

// Round 3
// 139.567 us; speedup vs baseline: 2.0773x; 2.0773x over previous
//
#include <hip/hip_runtime.h>
#include <cstdint>

#define B_ROWS 32768
#define DIM    256
#define KCODES 1024
#define NSPLIT 2

typedef _Float16 f16x8 __attribute__((ext_vector_type(8)));
typedef float    f32x4 __attribute__((ext_vector_type(4)));

// ws layout:
//   [0, 512K)        cb_hi  (fp16, per-code 512B rows, 16B-granule XOR-swizzled)
//   [512K, 1M)       cb_lo  (fp16, scaled x2048, same swizzle)
//   [1M, 1M+4K)      inv_norm (float[1024])
//   [1M+4K, ...)     cand   (float2[NSPLIT][B_ROWS] = {dot, bitcast(k)})

// ---------------- prep: codebook -> fp16 hi/lo (swizzled) + 1/norm ----------------
__global__ __launch_bounds__(64) void vq_prep(const float* __restrict__ cb,
                                              _Float16* __restrict__ hi,
                                              _Float16* __restrict__ lo,
                                              float* __restrict__ inv_norm) {
  const int k = blockIdx.x;
  const int lane = threadIdx.x;
  float4 c = reinterpret_cast<const float4*>(cb)[k * 64 + lane];
  float nrm = c.x * c.x + c.y * c.y + c.z * c.z + c.w * c.w;
#pragma unroll
  for (int off = 32; off; off >>= 1) nrm += __shfl_xor(nrm, off);
  if (lane == 0) inv_norm[k] = 1.0f / nrm;

  float f[4] = {c.x, c.y, c.z, c.w};
  _Float16 h[4], l[4];
#pragma unroll
  for (int i = 0; i < 4; ++i) {
    h[i] = (_Float16)f[i];
    l[i] = (_Float16)((f[i] - (float)h[i]) * 2048.0f);
  }
  // granule swizzle: phys = g ^ (code & 15) within the code's 512B row
  const int phys = (lane >> 1) ^ (k & 15);
  const int byteoff = k * 512 + phys * 16 + (lane & 1) * 8;
  *reinterpret_cast<uint2*>((char*)hi + byteoff) = *reinterpret_cast<uint2*>(h);
  *reinterpret_cast<uint2*>((char*)lo + byteoff) = *reinterpret_cast<uint2*>(l);
}

__device__ __forceinline__ void gld16(const void* g, void* l) {
  __builtin_amdgcn_global_load_lds(
      (const __attribute__((address_space(1))) uint32_t*)g,
      (__attribute__((address_space(3))) uint32_t*)l, 16, 0, 0);
}

// ---------------- main: split-fp16 MFMA GEMM + per-split argmax candidates ----------------
// K-split x2: block (rowblk, split) covers rows [rowblk*128, +128) x codes [split*512, +512).
// 32 rows/wave needs ~200 unified regs -> 2 waves/SIMD max; cap at 256 (NOT 128 — R2 spilled).
__global__ __launch_bounds__(256, 2) void vq_main(const float* __restrict__ emb,
                                                  const _Float16* __restrict__ cbh,
                                                  const _Float16* __restrict__ cbl,
                                                  const float* __restrict__ inv_g,
                                                  float2* __restrict__ cand) {
  __shared__ uint4 Btile[2][1024];   // 2 x 16KB: [0,8K) hi, [8K,16K) lo
  __shared__ float inv_s[KCODES];

  const int flat = threadIdx.x;
  const int wave = flat >> 6;
  const int lane = flat & 63;
  const int quad = lane >> 4;
  const int lr   = lane & 15;

  const int split  = blockIdx.x & (NSPLIT - 1);
  const int rowblk = blockIdx.x >> 1;
  const int t0 = split * 32;         // 32 t-iters of 16 codes each = 512 codes

  reinterpret_cast<float4*>(inv_s)[flat] = reinterpret_cast<const float4*>(inv_g)[flat];

  // A fragments: 32 rows/wave (2 subtiles of 16), whole K-depth, hi+lo, in registers.
  f16x8 Ah[2][8], Al[2][8];
  const int row0 = rowblk * 128 + wave * 32;
#pragma unroll
  for (int s = 0; s < 2; ++s) {
    const float* rp = emb + (size_t)(row0 + s * 16 + lr) * DIM;
#pragma unroll
    for (int c = 0; c < 8; ++c) {
      const float* p = rp + c * 32 + quad * 8;
      float4 f0 = *reinterpret_cast<const float4*>(p);
      float4 f1 = *reinterpret_cast<const float4*>(p + 4);
      float f[8] = {f0.x, f0.y, f0.z, f0.w, f1.x, f1.y, f1.z, f1.w};
      f16x8 h, l;
#pragma unroll
      for (int j = 0; j < 8; ++j) {
        _Float16 hv = (_Float16)f[j];
        h[j] = hv;
        l[j] = (_Float16)((f[j] - (float)hv) * 2048.0f);
      }
      Ah[s][c] = h;
      Al[s][c] = l;
    }
  }

  auto stage = [&](int buf, int t) {
    const char* srcH = (const char*)cbh + t * 8192;
    const char* srcL = (const char*)cbl + t * 8192;
    char* dst = (char*)&Btile[buf][0];
    const int off = flat * 16;
    gld16(srcH + off,        dst + off);
    gld16(srcH + 4096 + off, dst + 4096 + off);
    gld16(srcL + off,        dst + 8192 + off);
    gld16(srcL + 4096 + off, dst + 12288 + off);
  };
  stage(0, t0);

  float bg[2][4], bd[2][4];
  int   bk[2][4];
#pragma unroll
  for (int s = 0; s < 2; ++s)
#pragma unroll
    for (int r = 0; r < 4; ++r) { bg[s][r] = -1.0f; bd[s][r] = 0.0f; bk[s][r] = t0 * 16; }

  for (int t = t0; t < t0 + 32; ++t) {
    __syncthreads();
    if (t + 1 < t0 + 32) stage((t + 1) & 1, t + 1);
    const char* buf = (const char*)&Btile[t & 1][0];

    f32x4 accA0 = {0, 0, 0, 0}, accB0 = {0, 0, 0, 0};
    f32x4 accA1 = {0, 0, 0, 0}, accB1 = {0, 0, 0, 0};
#pragma unroll
    for (int c = 0; c < 8; ++c) {
      const int g = (((c * 4 + quad) ^ lr) * 16) + lr * 512;  // de-swizzled granule
      f16x8 bh = *reinterpret_cast<const f16x8*>(buf + g);
      f16x8 bl = *reinterpret_cast<const f16x8*>(buf + 8192 + g);
      accA0 = __builtin_amdgcn_mfma_f32_16x16x32_f16(Ah[0][c], bh, accA0, 0, 0, 0);
      accA1 = __builtin_amdgcn_mfma_f32_16x16x32_f16(Ah[1][c], bh, accA1, 0, 0, 0);
      accB0 = __builtin_amdgcn_mfma_f32_16x16x32_f16(Al[0][c], bh, accB0, 0, 0, 0);
      accB1 = __builtin_amdgcn_mfma_f32_16x16x32_f16(Al[1][c], bh, accB1, 0, 0, 0);
      accB0 = __builtin_amdgcn_mfma_f32_16x16x32_f16(Ah[0][c], bl, accB0, 0, 0, 0);
      accB1 = __builtin_amdgcn_mfma_f32_16x16x32_f16(Ah[1][c], bl, accB1, 0, 0, 0);
    }

    const int n = t * 16 + lr;             // C/D layout: col = lane&15
    const float inl = inv_s[n];
#pragma unroll
    for (int r = 0; r < 4; ++r) {
      float d0 = accA0[r] + accB0[r] * 4.8828125e-4f;   // 1/2048
      float g0 = d0 * d0 * inl;
      if (g0 > bg[0][r]) { bg[0][r] = g0; bd[0][r] = d0; bk[0][r] = n; }
      float d1 = accA1[r] + accB1[r] * 4.8828125e-4f;
      float g1 = d1 * d1 * inl;
      if (g1 > bg[1][r]) { bg[1][r] = g1; bd[1][r] = d1; bk[1][r] = n; }
    }
  }

  // cross-lane argmax over the 16 cols of each quad (rows = quad*4+reg per C layout)
#pragma unroll
  for (int s = 0; s < 2; ++s) {
#pragma unroll
    for (int r = 0; r < 4; ++r) {
      float g = bg[s][r]; int k = bk[s][r]; float d = bd[s][r];
#pragma unroll
      for (int m = 1; m < 16; m <<= 1) {
        float g2 = __shfl_xor(g, m);
        int   k2 = __shfl_xor(k, m);
        float d2 = __shfl_xor(d, m);
        if (g2 > g || (g2 == g && k2 < k)) { g = g2; k = k2; d = d2; }
      }
      if (lr == 0) {
        const int row = row0 + s * 16 + quad * 4 + r;
        cand[(size_t)split * B_ROWS + row] = make_float2(d, __int_as_float(k));
      }
    }
  }
}

// ---------------- reduce: pick best split candidate, write z + index ----------------
__global__ __launch_bounds__(256) void vq_reduce(const float2* __restrict__ cand,
                                                 const float* __restrict__ inv_g,
                                                 const float* __restrict__ cb,
                                                 float* __restrict__ out) {
  const int wave = threadIdx.x >> 6;
  const int lane = threadIdx.x & 63;
  const int row = blockIdx.x * 4 + wave;

  float best_g = -1.0f, best_d = 0.0f;
  int best_k = 0;
#pragma unroll
  for (int s = 0; s < NSPLIT; ++s) {
    float2 c = cand[(size_t)s * B_ROWS + row];
    int k = __float_as_int(c.y);
    float g = c.x * c.x * inv_g[k];
    if (g > best_g || (g == best_g && k < best_k)) {
      best_g = g; best_d = c.x; best_k = k;
    }
  }
  const float alpha = best_d * inv_g[best_k];
  float4 c4 = reinterpret_cast<const float4*>(cb)[best_k * 64 + lane];
  float4 z = {alpha * c4.x, alpha * c4.y, alpha * c4.z, alpha * c4.w};
  reinterpret_cast<float4*>(out)[(size_t)row * 64 + lane] = z;
  if (lane == 0) out[(size_t)B_ROWS * DIM + row] = (float)best_k;
}

extern "C" void kernel_launch(void* const* d_in, const int* in_sizes, int n_in,
                              void* d_out, int out_size, void* d_ws, size_t ws_size,
                              hipStream_t stream) {
  const float* emb = (const float*)d_in[0];
  const float* cb  = (const float*)d_in[1];
  _Float16* cbh = (_Float16*)d_ws;
  _Float16* cbl = (_Float16*)((char*)d_ws + (512 << 10));
  float*    inv = (float*)((char*)d_ws + (1 << 20));
  float2*   cand = (float2*)((char*)d_ws + (1 << 20) + 4096);

  vq_prep<<<KCODES, 64, 0, stream>>>(cb, cbh, cbl, inv);
  vq_main<<<(B_ROWS / 128) * NSPLIT, 256, 0, stream>>>(emb, cbh, cbl, inv, cand);
  vq_reduce<<<B_ROWS / 4, 256, 0, stream>>>(cand, inv, cb, (float*)d_out);
}